// Round 5
// baseline (118.753 us; speedup 1.0000x reference)
//
#include <hip/hip_runtime.h>
#include <stdint.h>

__device__ __forceinline__ float sgnf(float v) {
    return (v > 0.f) ? 1.f : ((v < 0.f) ? -1.f : 0.f);
}

// ---------------------------------------------------------------------------
// Fused kernel: one block = 8 channels, end-to-end.
// conv1 reads x rows directly from global (L1/L2-resident, 50KB shared by all
// blocks); zero-row in d_ws supplies the row(-1) pad; r[0]=0 is the col(-1)
// pad. h1 lives only in LDS. Tail = proven round-1 structure on 128 threads.
// ---------------------------------------------------------------------------
__global__ __launch_bounds__(256, 3) void hdc_fused(
    const float* __restrict__ x,
    const float* __restrict__ W1, const float* __restrict__ b1,
    const float* __restrict__ g1, const float* __restrict__ be1,
    const float* __restrict__ W2, const float* __restrict__ b2,
    const float* __restrict__ g2, const float* __restrict__ be2,
    const float* __restrict__ W3, const float* __restrict__ b3,
    const float* __restrict__ g3, const float* __restrict__ be3,
    const float* __restrict__ Wc, const float* __restrict__ zrow,
    float* __restrict__ out)
{
    __shared__ float w1s[8 * 25];
    __shared__ signed char h1s[8 * 2704];   // 21632 B
    __shared__ float redbuf[4][4];
    __shared__ float stats[4][2];
    __shared__ float h3buf[8 * 16];

    const int tid  = threadIdx.x;
    const int base = blockIdx.x * 8;

    // weights for all 8 channels into LDS (sign applied once)
    for (int i = tid; i < 200; i += 256)
        w1s[i] = sgnf(W1[base * 25 + i]);
    __syncthreads();

    const bool act = (tid < 208);
    const int oy = tid >> 4, bb = tid & 15;
    const int wv = tid >> 6, ln = tid & 63;

    // ---- conv1 + BN1 + binarize: two sweeps of 4 channels ----
    for (int sg = 0; sg < 2; ++sg) {
        const int d0 = base + sg * 4;

        float acc[4][13];
        #pragma unroll
        for (int c = 0; c < 4; ++c) {
            const float bv = b1[d0 + c];
            #pragma unroll
            for (int i = 0; i < 13; ++i) acc[c][i] = bv;
        }

        if (act) {
            #pragma unroll
            for (int ky = 0; ky < 5; ++ky) {
                const int rr_ = 2 * oy - 1 + ky;           // -1..27
                const float* rp = (rr_ >= 0) ? (x + bb * 784 + rr_ * 28) : zrow;
                float r[29];
                r[0] = 0.f;                                 // col -1 pad
                #pragma unroll
                for (int j = 0; j < 7; ++j) {
                    float4 v = ((const float4*)rp)[j];
                    r[4 * j + 1] = v.x; r[4 * j + 2] = v.y;
                    r[4 * j + 3] = v.z; r[4 * j + 4] = v.w;
                }
                #pragma unroll
                for (int kx = 0; kx < 5; ++kx) {
                    #pragma unroll
                    for (int c = 0; c < 4; ++c) {
                        const float wk = w1s[(sg * 4 + c) * 25 + 5 * ky + kx];
                        #pragma unroll
                        for (int ox = 0; ox < 13; ++ox)
                            acc[c][ox] = fmaf(r[2 * ox + kx], wk, acc[c][ox]);
                    }
                }
            }
        }

        // pass 1: means (identical reduction order to verified kernels)
        float s[4] = {0.f, 0.f, 0.f, 0.f};
        if (act) {
            #pragma unroll
            for (int c = 0; c < 4; ++c)
                #pragma unroll
                for (int i = 0; i < 13; ++i) s[c] += acc[c][i];
        }
        #pragma unroll
        for (int m = 32; m >= 1; m >>= 1)
            #pragma unroll
            for (int c = 0; c < 4; ++c) s[c] += __shfl_xor(s[c], m, 64);
        if (ln == 0) {
            #pragma unroll
            for (int c = 0; c < 4; ++c) redbuf[wv][c] = s[c];
        }
        __syncthreads();
        if (tid < 4) {
            float t = redbuf[0][tid] + redbuf[1][tid] + redbuf[2][tid] + redbuf[3][tid];
            stats[tid][0] = t / 2704.f;
        }
        __syncthreads();

        // pass 2: variances (two-pass, mirrors jnp.var)
        float dv[4] = {0.f, 0.f, 0.f, 0.f};
        if (act) {
            #pragma unroll
            for (int c = 0; c < 4; ++c) {
                const float mu = stats[c][0];
                #pragma unroll
                for (int i = 0; i < 13; ++i) {
                    const float e = acc[c][i] - mu;
                    dv[c] = fmaf(e, e, dv[c]);
                }
            }
        }
        #pragma unroll
        for (int m = 32; m >= 1; m >>= 1)
            #pragma unroll
            for (int c = 0; c < 4; ++c) dv[c] += __shfl_xor(dv[c], m, 64);
        if (ln == 0) {
            #pragma unroll
            for (int c = 0; c < 4; ++c) redbuf[wv][c] = dv[c];
        }
        __syncthreads();
        if (tid < 4) {
            float t = redbuf[0][tid] + redbuf[1][tid] + redbuf[2][tid] + redbuf[3][tid];
            stats[tid][1] = rsqrtf(t / 2704.f + 1e-5f);
        }
        __syncthreads();

        if (act) {
            #pragma unroll
            for (int c = 0; c < 4; ++c) {
                const float mu = stats[c][0], iv = stats[c][1];
                const float ga = g1[d0 + c], bea = be1[d0 + c];
                signed char* hp = &h1s[(sg * 4 + c) * 2704 + bb * 169 + oy * 13];
                #pragma unroll
                for (int i = 0; i < 13; ++i) {
                    const float xn = (acc[c][i] - mu) * iv;
                    const float y  = fmaf(xn, ga, bea);
                    const float z  = ((y > 0.f) ? y : 0.01f * y) - 0.5f;
                    hp[i] = (z > 0.f) ? 1 : ((z < 0.f) ? -1 : 0);
                }
            }
        }
        // no barrier needed between sweeps: next sweep's redbuf barrier
        // orders stats/redbuf reuse; h1s regions are disjoint per sweep.
    }
    __syncthreads();   // h1s complete for all 8 channels

    // ---- tail: conv2 + BN2 + sign + conv3 + BN3 + sign (proven structure) ----
    if (tid < 128) {
        const int ch = tid >> 4, b_ = tid & 15;
        const int d = base + ch;
        float sw2[9];
        #pragma unroll
        for (int k = 0; k < 9; ++k) sw2[k] = sgnf(W2[d * 9 + k]);
        const float b2v = b2[d];
        const signed char* hp = &h1s[ch * 2704 + b_ * 169];

        float c2[36];
        #pragma unroll
        for (int oy2 = 0; oy2 < 6; ++oy2) {
            float rr[3][13];
            #pragma unroll
            for (int ky = 0; ky < 3; ++ky)
                #pragma unroll
                for (int j = 0; j < 13; ++j)
                    rr[ky][j] = (float)hp[(2 * oy2 + ky) * 13 + j];
            #pragma unroll
            for (int ox2 = 0; ox2 < 6; ++ox2) {
                float s = b2v;
                #pragma unroll
                for (int ky = 0; ky < 3; ++ky)
                    #pragma unroll
                    for (int kx = 0; kx < 3; ++kx)
                        s = fmaf(rr[ky][2 * ox2 + kx], sw2[3 * ky + kx], s);
                c2[oy2 * 6 + ox2] = s;
            }
        }

        // BN2 over (b, 6, 6): exact small integers
        float s2 = 0.f;
        #pragma unroll
        for (int i = 0; i < 36; ++i) s2 += c2[i];
        #pragma unroll
        for (int m = 8; m >= 1; m >>= 1) s2 += __shfl_xor(s2, m, 16);
        const float mu2 = s2 / 576.f;
        float d2 = 0.f;
        #pragma unroll
        for (int i = 0; i < 36; ++i) { const float e = c2[i] - mu2; d2 = fmaf(e, e, d2); }
        #pragma unroll
        for (int m = 8; m >= 1; m >>= 1) d2 += __shfl_xor(d2, m, 16);
        const float inv2 = rsqrtf(d2 / 576.f + 1e-5f);
        const float g2v = g2[d], be2v = be2[d];

        // binarize h2 fused into conv3
        float z3 = b3[d];
        #pragma unroll
        for (int i = 0; i < 36; ++i) {
            const float xn = (c2[i] - mu2) * inv2;
            const float y  = fmaf(xn, g2v, be2v);
            const float z  = ((y > 0.f) ? y : 0.01f * y) - 0.5f;
            const float h2 = (z > 0.f) ? 1.f : ((z < 0.f) ? -1.f : 0.f);
            z3 = fmaf(h2, W3[d * 36 + i], z3);
        }

        // BN3 over batch (16 lanes)
        float s3 = z3;
        #pragma unroll
        for (int m = 8; m >= 1; m >>= 1) s3 += __shfl_xor(s3, m, 16);
        const float mu3 = s3 / 16.f;
        const float e3 = z3 - mu3;
        float d3 = e3 * e3;
        #pragma unroll
        for (int m = 8; m >= 1; m >>= 1) d3 += __shfl_xor(d3, m, 16);
        const float inv3 = rsqrtf(d3 / 16.f + 1e-5f);
        const float xn3 = (z3 - mu3) * inv3;
        const float y3  = fmaf(xn3, g3[d], be3[d]);
        const float zz  = ((y3 > 0.f) ? y3 : 0.01f * y3) - 0.5f;
        h3buf[tid] = (zz > 0.f) ? 1.f : ((zz < 0.f) ? -1.f : 0.f);
    }
    __syncthreads();

    // ---- per-block class partials: exact-integer atomic accumulation ----
    if (tid < 160) {
        const int bq = tid / 10, cq = tid - bq * 10;
        float ssum = 0.f;
        #pragma unroll
        for (int ch = 0; ch < 8; ++ch)
            ssum += h3buf[ch * 16 + bq] * sgnf(Wc[cq * 10000 + base + ch]);
        atomicAdd(&out[bq * 10 + cq], ssum);
    }
}

// ---------------------------------------------------------------------------
// Final scale: sims / sqrt(10000) == /100 exactly
// ---------------------------------------------------------------------------
__global__ void hdc_scale(float* __restrict__ out) {
    const int i = threadIdx.x;
    if (i < 160) out[i] = out[i] / 100.0f;
}

extern "C" void kernel_launch(void* const* d_in, const int* in_sizes, int n_in,
                              void* d_out, int out_size, void* d_ws, size_t ws_size,
                              hipStream_t stream) {
    const float* x   = (const float*)d_in[0];
    const float* W1  = (const float*)d_in[1];
    const float* b1  = (const float*)d_in[2];
    const float* g1  = (const float*)d_in[3];
    const float* be1 = (const float*)d_in[4];
    const float* W2  = (const float*)d_in[5];
    const float* b2  = (const float*)d_in[6];
    const float* g2  = (const float*)d_in[7];
    const float* be2 = (const float*)d_in[8];
    const float* W3  = (const float*)d_in[9];
    const float* b3  = (const float*)d_in[10];
    const float* g3  = (const float*)d_in[11];
    const float* be3 = (const float*)d_in[12];
    const float* Wc  = (const float*)d_in[13];
    float* out = (float*)d_out;
    float* zrow = (float*)d_ws;              // 112 B of zeros (row -1 pad)

    hipMemsetAsync(out, 0, 160 * sizeof(float), stream);
    hipMemsetAsync(zrow, 0, 128, stream);

    hdc_fused<<<dim3(1250), dim3(256), 0, stream>>>(
        x, W1, b1, g1, be1, W2, b2, g2, be2, W3, b3, g3, be3, Wc, zrow, out);
    hdc_scale<<<dim3(1), dim3(192), 0, stream>>>(out);
}

// Round 6
// 81.836 us; speedup vs baseline: 1.4511x; 1.4511x over previous
//
#include <hip/hip_runtime.h>
#include <stdint.h>

__device__ __forceinline__ float sgnf(float v) {
    return (v > 0.f) ? 1.f : ((v < 0.f) ? -1.f : 0.f);
}

// ---------------------------------------------------------------------------
// Fused kernel: one block = 8 channels, end-to-end.
// conv1 reads x rows directly from global (50KB, L2-resident, shared by all
// blocks); zero-row in d_ws supplies the row(-1) pad; r[0]=0 is the col(-1)
// pad. Conv sweeps are 2 channels each (proven ~110-VGPR no-spill shape).
// h1 lives only in LDS. Tail = proven round-1 structure on 128 threads.
// ---------------------------------------------------------------------------
__global__ __launch_bounds__(256, 2) void hdc_fused(
    const float* __restrict__ x,
    const float* __restrict__ W1, const float* __restrict__ b1,
    const float* __restrict__ g1, const float* __restrict__ be1,
    const float* __restrict__ W2, const float* __restrict__ b2,
    const float* __restrict__ g2, const float* __restrict__ be2,
    const float* __restrict__ W3, const float* __restrict__ b3,
    const float* __restrict__ g3, const float* __restrict__ be3,
    const float* __restrict__ Wc, const float* __restrict__ zrow,
    float* __restrict__ out)
{
    __shared__ float w1s[8 * 25];
    __shared__ signed char h1s[8 * 2704];   // 21632 B
    __shared__ float redbuf[4][4];
    __shared__ float stats[2][2];
    __shared__ float h3buf[8 * 16];

    const int tid  = threadIdx.x;
    const int base = blockIdx.x * 8;

    // weights for all 8 channels into LDS (sign applied once)
    for (int i = tid; i < 200; i += 256)
        w1s[i] = sgnf(W1[base * 25 + i]);
    __syncthreads();

    const bool act = (tid < 208);
    const int oy = tid >> 4, bb = tid & 15;
    const int wv = tid >> 6, ln = tid & 63;

    // ---- conv1 + BN1 + binarize: four sweeps of 2 channels ----
    for (int sg = 0; sg < 4; ++sg) {
        const int d0 = base + 2 * sg, d1 = d0 + 1;

        float wa[25], wb[25];
        #pragma unroll
        for (int k = 0; k < 25; ++k) {
            wa[k] = w1s[(2 * sg) * 25 + k];
            wb[k] = w1s[(2 * sg + 1) * 25 + k];
        }
        const float b1a = b1[d0], b1b = b1[d1];
        float fa[13], fb[13];
        #pragma unroll
        for (int i = 0; i < 13; ++i) { fa[i] = b1a; fb[i] = b1b; }

        if (act) {
            #pragma unroll
            for (int ky = 0; ky < 5; ++ky) {
                const int rr_ = 2 * oy - 1 + ky;           // -1..27
                const float* rp = (rr_ >= 0) ? (x + bb * 784 + rr_ * 28) : zrow;
                float r[29];
                r[0] = 0.f;                                 // col -1 pad
                #pragma unroll
                for (int j = 0; j < 7; ++j) {
                    float4 v = ((const float4*)rp)[j];
                    r[4 * j + 1] = v.x; r[4 * j + 2] = v.y;
                    r[4 * j + 3] = v.z; r[4 * j + 4] = v.w;
                }
                #pragma unroll
                for (int kx = 0; kx < 5; ++kx) {
                    const float wka = wa[5 * ky + kx], wkb = wb[5 * ky + kx];
                    #pragma unroll
                    for (int ox = 0; ox < 13; ++ox) {
                        const float xv = r[2 * ox + kx];
                        fa[ox] = fmaf(xv, wka, fa[ox]);
                        fb[ox] = fmaf(xv, wkb, fb[ox]);
                    }
                }
            }
        }

        // pass 1: means (identical reduction order to verified kernels)
        float sa = 0.f, sb = 0.f;
        if (act) {
            #pragma unroll
            for (int i = 0; i < 13; ++i) { sa += fa[i]; sb += fb[i]; }
        }
        #pragma unroll
        for (int m = 32; m >= 1; m >>= 1) {
            sa += __shfl_xor(sa, m, 64);
            sb += __shfl_xor(sb, m, 64);
        }
        if (ln == 0) { redbuf[wv][0] = sa; redbuf[wv][1] = sb; }
        __syncthreads();
        if (tid == 0) {
            float ta = redbuf[0][0] + redbuf[1][0] + redbuf[2][0] + redbuf[3][0];
            float tb = redbuf[0][1] + redbuf[1][1] + redbuf[2][1] + redbuf[3][1];
            stats[0][0] = ta / 2704.f;
            stats[1][0] = tb / 2704.f;
        }
        __syncthreads();
        const float mua = stats[0][0], mub = stats[1][0];

        // pass 2: variances (two-pass, mirrors jnp.var)
        float da = 0.f, db = 0.f;
        if (act) {
            #pragma unroll
            for (int i = 0; i < 13; ++i) {
                const float ea = fa[i] - mua, eb = fb[i] - mub;
                da = fmaf(ea, ea, da);
                db = fmaf(eb, eb, db);
            }
        }
        #pragma unroll
        for (int m = 32; m >= 1; m >>= 1) {
            da += __shfl_xor(da, m, 64);
            db += __shfl_xor(db, m, 64);
        }
        if (ln == 0) { redbuf[wv][2] = da; redbuf[wv][3] = db; }
        __syncthreads();
        if (tid == 0) {
            float ta = redbuf[0][2] + redbuf[1][2] + redbuf[2][2] + redbuf[3][2];
            float tb = redbuf[0][3] + redbuf[1][3] + redbuf[2][3] + redbuf[3][3];
            stats[0][1] = rsqrtf(ta / 2704.f + 1e-5f);
            stats[1][1] = rsqrtf(tb / 2704.f + 1e-5f);
        }
        __syncthreads();

        if (act) {
            const float iva = stats[0][1], ivb = stats[1][1];
            const float ga = g1[d0], gb = g1[d1];
            const float bea = be1[d0], beb = be1[d1];
            signed char* ha = &h1s[(2 * sg) * 2704 + bb * 169 + oy * 13];
            signed char* hb = &h1s[(2 * sg + 1) * 2704 + bb * 169 + oy * 13];
            #pragma unroll
            for (int i = 0; i < 13; ++i) {
                const float xna = (fa[i] - mua) * iva;
                const float ya  = fmaf(xna, ga, bea);
                const float za  = ((ya > 0.f) ? ya : 0.01f * ya) - 0.5f;
                ha[i] = (za > 0.f) ? 1 : ((za < 0.f) ? -1 : 0);
                const float xnb = (fb[i] - mub) * ivb;
                const float yb  = fmaf(xnb, gb, beb);
                const float zb  = ((yb > 0.f) ? yb : 0.01f * yb) - 0.5f;
                hb[i] = (zb > 0.f) ? 1 : ((zb < 0.f) ? -1 : 0);
            }
        }
        __syncthreads();   // stats/redbuf reuse next sweep; h1s region done
    }

    // ---- tail: conv2 + BN2 + sign + conv3 + BN3 + sign (proven structure) ----
    if (tid < 128) {
        const int ch = tid >> 4, b_ = tid & 15;
        const int d = base + ch;
        float sw2[9];
        #pragma unroll
        for (int k = 0; k < 9; ++k) sw2[k] = sgnf(W2[d * 9 + k]);
        const float b2v = b2[d];
        const signed char* hp = &h1s[ch * 2704 + b_ * 169];

        float c2[36];
        #pragma unroll
        for (int oy2 = 0; oy2 < 6; ++oy2) {
            float rr[3][13];
            #pragma unroll
            for (int ky = 0; ky < 3; ++ky)
                #pragma unroll
                for (int j = 0; j < 13; ++j)
                    rr[ky][j] = (float)hp[(2 * oy2 + ky) * 13 + j];
            #pragma unroll
            for (int ox2 = 0; ox2 < 6; ++ox2) {
                float s = b2v;
                #pragma unroll
                for (int ky = 0; ky < 3; ++ky)
                    #pragma unroll
                    for (int kx = 0; kx < 3; ++kx)
                        s = fmaf(rr[ky][2 * ox2 + kx], sw2[3 * ky + kx], s);
                c2[oy2 * 6 + ox2] = s;
            }
        }

        // BN2 over (b, 6, 6): exact small integers
        float s2 = 0.f;
        #pragma unroll
        for (int i = 0; i < 36; ++i) s2 += c2[i];
        #pragma unroll
        for (int m = 8; m >= 1; m >>= 1) s2 += __shfl_xor(s2, m, 16);
        const float mu2 = s2 / 576.f;
        float d2 = 0.f;
        #pragma unroll
        for (int i = 0; i < 36; ++i) { const float e = c2[i] - mu2; d2 = fmaf(e, e, d2); }
        #pragma unroll
        for (int m = 8; m >= 1; m >>= 1) d2 += __shfl_xor(d2, m, 16);
        const float inv2 = rsqrtf(d2 / 576.f + 1e-5f);
        const float g2v = g2[d], be2v = be2[d];

        // binarize h2 fused into conv3
        float z3 = b3[d];
        #pragma unroll
        for (int i = 0; i < 36; ++i) {
            const float xn = (c2[i] - mu2) * inv2;
            const float y  = fmaf(xn, g2v, be2v);
            const float z  = ((y > 0.f) ? y : 0.01f * y) - 0.5f;
            const float h2 = (z > 0.f) ? 1.f : ((z < 0.f) ? -1.f : 0.f);
            z3 = fmaf(h2, W3[d * 36 + i], z3);
        }

        // BN3 over batch (16 lanes)
        float s3 = z3;
        #pragma unroll
        for (int m = 8; m >= 1; m >>= 1) s3 += __shfl_xor(s3, m, 16);
        const float mu3 = s3 / 16.f;
        const float e3 = z3 - mu3;
        float d3 = e3 * e3;
        #pragma unroll
        for (int m = 8; m >= 1; m >>= 1) d3 += __shfl_xor(d3, m, 16);
        const float inv3 = rsqrtf(d3 / 16.f + 1e-5f);
        const float xn3 = (z3 - mu3) * inv3;
        const float y3  = fmaf(xn3, g3[d], be3[d]);
        const float zz  = ((y3 > 0.f) ? y3 : 0.01f * y3) - 0.5f;
        h3buf[tid] = (zz > 0.f) ? 1.f : ((zz < 0.f) ? -1.f : 0.f);
    }
    __syncthreads();

    // ---- per-block class partials: exact-integer atomic accumulation ----
    if (tid < 160) {
        const int bq = tid / 10, cq = tid - bq * 10;
        float ssum = 0.f;
        #pragma unroll
        for (int ch = 0; ch < 8; ++ch)
            ssum += h3buf[ch * 16 + bq] * sgnf(Wc[cq * 10000 + base + ch]);
        atomicAdd(&out[bq * 10 + cq], ssum);
    }
}

// ---------------------------------------------------------------------------
// Final scale: sims / sqrt(10000) == /100 exactly
// ---------------------------------------------------------------------------
__global__ void hdc_scale(float* __restrict__ out) {
    const int i = threadIdx.x;
    if (i < 160) out[i] = out[i] / 100.0f;
}

extern "C" void kernel_launch(void* const* d_in, const int* in_sizes, int n_in,
                              void* d_out, int out_size, void* d_ws, size_t ws_size,
                              hipStream_t stream) {
    const float* x   = (const float*)d_in[0];
    const float* W1  = (const float*)d_in[1];
    const float* b1  = (const float*)d_in[2];
    const float* g1  = (const float*)d_in[3];
    const float* be1 = (const float*)d_in[4];
    const float* W2  = (const float*)d_in[5];
    const float* b2  = (const float*)d_in[6];
    const float* g2  = (const float*)d_in[7];
    const float* be2 = (const float*)d_in[8];
    const float* W3  = (const float*)d_in[9];
    const float* b3  = (const float*)d_in[10];
    const float* g3  = (const float*)d_in[11];
    const float* be3 = (const float*)d_in[12];
    const float* Wc  = (const float*)d_in[13];
    float* out = (float*)d_out;
    float* zrow = (float*)d_ws;              // 112 B of zeros (row -1 pad)

    hipMemsetAsync(out, 0, 160 * sizeof(float), stream);
    hipMemsetAsync(zrow, 0, 128, stream);

    hdc_fused<<<dim3(1250), dim3(256), 0, stream>>>(
        x, W1, b1, g1, be1, W2, b2, g2, be2, W3, b3, g3, be3, Wc, zrow, out);
    hdc_scale<<<dim3(1), dim3(192), 0, stream>>>(out);
}